// Round 1
// baseline (692.473 us; speedup 1.0000x reference)
//
#include <hip/hip_runtime.h>

constexpr int Dn  = 33;
constexpr int HSn = 1024;
constexpr int WPB = 4;   // waves per block
constexpr int RPW = 4;   // rows per wave
constexpr int CHUNKS = HSn / (WPB * RPW);  // 64 row-chunks per d

// Consume staged weights w[0..3] against vector v into s, then (optionally)
// refill w[] with the next row's data. The refill loads are issued interleaved
// with the FMAs so ~24 loads stay in flight across the reduce/epilogue.
__device__ __forceinline__ void consume_refill(float4 (&w)[4],
                                               const float4 (&v)[4],
                                               const float4* __restrict__ p,
                                               int nOff, int lane, bool refill,
                                               float& s) {
    #pragma unroll
    for (int k = 0; k < 4; ++k) {
        s += w[k].x * v[k].x;
        s += w[k].y * v[k].y;
        s += w[k].z * v[k].z;
        s += w[k].w * v[k].w;
        if (refill) w[k] = p[nOff + k * 64 + lane];
    }
}

__global__ __launch_bounds__(WPB * 64, 3)
void tmgru_kernel(const float* __restrict__ H,
                  const float* __restrict__ x,
                  const float* __restrict__ h,
                  const float* __restrict__ W_z,
                  const float* __restrict__ U_zx,
                  const float* __restrict__ U_zh,
                  const float* __restrict__ W_r,
                  const float* __restrict__ U_rx,
                  const float* __restrict__ U_rh,
                  const float* __restrict__ W_h,
                  const float* __restrict__ U_hx,
                  const float* __restrict__ U_hh,
                  const float* __restrict__ b_z,
                  const float* __restrict__ b_r,
                  const float* __restrict__ b_h,
                  float* __restrict__ out)
{
    const int lane  = threadIdx.x & 63;
    const int wv    = threadIdx.x >> 6;
    const int d     = blockIdx.x / CHUNKS;
    const int chunk = blockIdx.x % CHUNKS;
    const int row0  = chunk * (WPB * RPW) + wv * RPW;

    // Stage H[d,:] and h[:] in registers: lane owns float4 slots {k*64+lane}.
    float4 a[4], b[4];
    {
        const float4* Hp = (const float4*)(H + (size_t)d * HSn);
        const float4* hp = (const float4*)h;
        #pragma unroll
        for (int k = 0; k < 4; ++k) {
            a[k] = Hp[k * 64 + lane];
            b[k] = hp[k * 64 + lane];
        }
    }
    const float xd = x[d];

    // Row-0 base of this wave's slab in each weight matrix (float4 units).
    const size_t base0 = ((size_t)d * HSn + row0) * HSn;
    const float4* pWz  = (const float4*)(W_z  + base0);
    const float4* pUzh = (const float4*)(U_zh + base0);
    const float4* pWr  = (const float4*)(W_r  + base0);
    const float4* pUrh = (const float4*)(U_rh + base0);
    const float4* pWh  = (const float4*)(W_h  + base0);
    const float4* pUhh = (const float4*)(U_hh + base0);
    constexpr int ROWF4 = HSn / 4;  // 256 float4 per row

    // Prologue: batch-issue all 24 loads for row 0 (24-deep MLP from the start).
    float4 wz[4], wzh[4], wr[4], wrh[4], wh[4], whh[4];
    #pragma unroll
    for (int k = 0; k < 4; ++k) wz[k]  = pWz [k * 64 + lane];
    #pragma unroll
    for (int k = 0; k < 4; ++k) wzh[k] = pUzh[k * 64 + lane];
    #pragma unroll
    for (int k = 0; k < 4; ++k) wr[k]  = pWr [k * 64 + lane];
    #pragma unroll
    for (int k = 0; k < 4; ++k) wrh[k] = pUrh[k * 64 + lane];
    #pragma unroll
    for (int k = 0; k < 4; ++k) wh[k]  = pWh [k * 64 + lane];
    #pragma unroll
    for (int k = 0; k < 4; ++k) whh[k] = pUhh[k * 64 + lane];

    #pragma unroll
    for (int r = 0; r < RPW; ++r) {
        const int    i  = row0 + r;
        const size_t di = (size_t)d * HSn + i;

        // Issue epilogue scalar loads early; latency hides under the FMA phase.
        const float uzx = U_zx[di];
        const float urx = U_rx[di];
        const float uhx = U_hx[di];
        const float bz  = b_z[i];
        const float br  = b_r[i];
        const float bh  = b_h[i];
        const float Hdi = H[di];

        const bool refill = (r + 1 < RPW);
        const int  nOff   = (r + 1) * ROWF4;  // next row, float4 units

        float s0 = 0.f, s1 = 0.f, s2 = 0.f, s3 = 0.f, s4 = 0.f, s5 = 0.f;
        consume_refill(wz,  a, pWz,  nOff, lane, refill, s0);
        consume_refill(wzh, b, pUzh, nOff, lane, refill, s1);
        consume_refill(wr,  a, pWr,  nOff, lane, refill, s2);
        consume_refill(wrh, b, pUrh, nOff, lane, refill, s3);
        consume_refill(wh,  a, pWh,  nOff, lane, refill, s4);
        consume_refill(whh, b, pUhh, nOff, lane, refill, s5);

        // Wave-64 butterfly reduction of the six dot products.
        // Next row's 24 loads are already in flight behind this.
        #pragma unroll
        for (int off = 32; off > 0; off >>= 1) {
            s0 += __shfl_xor(s0, off, 64);
            s1 += __shfl_xor(s1, off, 64);
            s2 += __shfl_xor(s2, off, 64);
            s3 += __shfl_xor(s3, off, 64);
            s4 += __shfl_xor(s4, off, 64);
            s5 += __shfl_xor(s5, off, 64);
        }

        const float z_pre = s0 + uzx * xd + s1 + bz;
        const float r_pre = s2 + urx * xd + s3 + br;
        const float zt = 1.f / (1.f + __expf(-z_pre));
        const float rt = 1.f / (1.f + __expf(-r_pre));
        const float hh_ = tanhf(rt * s4 + uhx * xd + s5 + bh);
        const float o   = zt * Hdi + (1.f - zt) * hh_;

        if (lane == 0) out[di] = o;
    }
}

extern "C" void kernel_launch(void* const* d_in, const int* in_sizes, int n_in,
                              void* d_out, int out_size, void* d_ws, size_t ws_size,
                              hipStream_t stream) {
    const float* H    = (const float*)d_in[0];
    const float* x    = (const float*)d_in[1];
    const float* h    = (const float*)d_in[2];
    const float* W_z  = (const float*)d_in[3];
    const float* U_zx = (const float*)d_in[4];
    const float* U_zh = (const float*)d_in[5];
    const float* W_r  = (const float*)d_in[6];
    const float* U_rx = (const float*)d_in[7];
    const float* U_rh = (const float*)d_in[8];
    const float* W_h  = (const float*)d_in[9];
    const float* U_hx = (const float*)d_in[10];
    const float* U_hh = (const float*)d_in[11];
    const float* b_z  = (const float*)d_in[12];
    const float* b_r  = (const float*)d_in[13];
    const float* b_h  = (const float*)d_in[14];
    float* out = (float*)d_out;

    const int grid = Dn * CHUNKS;  // 33 * 64 = 2112 blocks
    tmgru_kernel<<<grid, WPB * 64, 0, stream>>>(
        H, x, h, W_z, U_zx, U_zh, W_r, U_rx, U_rh, W_h, U_hx, U_hh,
        b_z, b_r, b_h, out);
}